// Round 16
// baseline (16.062 us; speedup 1.0000x reference)
//
#include <hip/hip_runtime.h>

typedef float f2 __attribute__((ext_vector_type(2)));

#define N_QUBITS 5
#define DIM 32

// ---------- verified perm machinery (rounds 1/2/7-15) ----------
__host__ __device__ constexpr int cnot_apply(int i, int ctrl, int tgt) {
    const int pc = N_QUBITS - 1 - ctrl;
    const int pt = N_QUBITS - 1 - tgt;
    return i ^ (((i >> pc) & 1) << pt);
}
__host__ __device__ constexpr int layer_perm(int i, int r) {
    int idx = i;
    for (int q = N_QUBITS - 1; q >= 0; --q)
        idx = cnot_apply(idx, q, (q + r) % N_QUBITS);
    return idx;
}
__host__ __device__ constexpr int invP1(int p) {   // inverse of layer_perm(.,1)
    for (int l = 0; l < 32; ++l) if (layer_perm(l, 1) == p) return l;
    return 0;
}

// r15 kernel verbatim; ONLY change: __launch_bounds__(256,2) -> (256,3).
// Experiment: does 128-reg state + temps fit the 170-VGPR 3-wave budget
// without array demotion? (r13's demotion signature: VGPR=64, FETCH>>10MB)
__global__ __launch_bounds__(256, 3) void vqc_kernel(
    const float* __restrict__ x,      // (B, 5)
    const float* __restrict__ w,      // (2, 5, 3)
    const float* __restrict__ fc_w,   // (8, 5)
    const float* __restrict__ fc_b,   // (8,)
    float* __restrict__ out,          // (B, 8)
    int Btot)
{
    // ---- block-uniform precompute (r14/r15-verified preamble) ----
    __shared__ float s_g0[N_QUBITS][8];   // layer 0: full Rot coeffs
    __shared__ float s_cs[N_QUBITS][2];   // layer 1: (cos(th/2), sin(th/2))
    __shared__ float s_phr[DIM];          // layer-1 phi-diagonal, re
    __shared__ float s_phi[DIM];          // layer-1 phi-diagonal, im
    __shared__ float s_fc_w[40];
    __shared__ float s_fc_b[8];

    const int t = threadIdx.x;
    if (t < N_QUBITS) {                   // layer-0 gates: full matrix
        const float phi = w[t * 3 + 0];
        const float th  = w[t * 3 + 1];
        const float om  = w[t * 3 + 2];
        float s, c;   sincosf(0.5f * th, &s, &c);
        float sp, cp; sincosf(0.5f * (phi + om), &sp, &cp);
        float sm, cm; sincosf(0.5f * (phi - om), &sm, &cm);
        s_g0[t][0] =  cp * c;  s_g0[t][1] = -sp * c;   // g00
        s_g0[t][2] = -cm * s;  s_g0[t][3] = -sm * s;   // g01
        s_g0[t][4] =  cm * s;  s_g0[t][5] = -sm * s;   // g10
        s_g0[t][6] =  cp * c;  s_g0[t][7] =  sp * c;   // g11
    } else if (t >= 8 && t < 13) {        // layer-1 RY coeffs
        const int q = t - 8;
        float s, c;
        sincosf(0.5f * w[(N_QUBITS + q) * 3 + 1], &s, &c);
        s_cs[q][0] = c;  s_cs[q][1] = s;
    } else if (t >= 32 && t < 64) {       // layer-1 phi-diagonal (32 phases)
        const int j = t - 32;
        const int i = invP1(j);
        float ang = 0.f;
#pragma unroll
        for (int q = 0; q < N_QUBITS; ++q) {
            const float ph = w[(N_QUBITS + q) * 3 + 0];
            ang += ((i >> (4 - q)) & 1) ? 0.5f * ph : -0.5f * ph;
        }
        float s, c;
        sincosf(ang, &s, &c);
        s_phr[j] = c;  s_phi[j] = s;
    } else if (t >= 64 && t < 104) {
        s_fc_w[t - 64] = fc_w[t - 64];
    } else if (t >= 104 && t < 112) {
        s_fc_b[t - 104] = fc_b[t - 104];
    }
    __syncthreads();

    const int b0 = blockIdx.x * 512 + t;
    if (b0 >= Btot) return;
    const int b1 = b0 + 256;
    const int b1c = (b1 < Btot) ? b1 : b0;        // clamp for loads only

    const float* xp0 = x + (size_t)b0 * 5;
    const float* xp1 = x + (size_t)b1c * 5;

    // ---- build: post-layer-0 product state (r10/r15 verbatim, packed f2 SoA) ----
    f2 sre[DIM], sim[DIM];
    {
        float s0, c0, s1, c1;
        __sincosf(0.5f * xp0[0], &s0, &c0);
        __sincosf(0.5f * xp1[0], &s1, &c1);
        const f2 cc = f2{c0, c1}, ss = f2{s0, s1};
        sre[0]  = s_g0[0][0] * cc + s_g0[0][3] * ss;
        sim[0]  = s_g0[0][1] * cc - s_g0[0][2] * ss;
        sre[16] = s_g0[0][4] * cc + s_g0[0][7] * ss;
        sim[16] = s_g0[0][5] * cc - s_g0[0][6] * ss;
    }
#pragma unroll
    for (int q = 1; q < N_QUBITS; ++q) {
        float s0, c0, s1, c1;
        __sincosf(0.5f * xp0[q], &s0, &c0);
        __sincosf(0.5f * xp1[q], &s1, &c1);
        const f2 cc = f2{c0, c1}, ss = f2{s0, s1};
        const f2 v0re = s_g0[q][0] * cc + s_g0[q][3] * ss;
        const f2 v0im = s_g0[q][1] * cc - s_g0[q][2] * ss;
        const f2 v1re = s_g0[q][4] * cc + s_g0[q][7] * ss;
        const f2 v1im = s_g0[q][5] * cc - s_g0[q][6] * ss;
        const int stride = 1 << (4 - q);
#pragma unroll
        for (int k = 0; k < (1 << q); ++k) {
            const int m = k * (stride << 1);
            const f2 are = sre[m], aim = sim[m];
            sre[m + stride] = v1re * are - v1im * aim;
            sim[m + stride] = v1re * aim + v1im * are;
            sre[m]          = v0re * are - v0im * aim;
            sim[m]          = v0re * aim + v0im * are;
        }
    }

    // ---- layer-1 phi-diagonal: st[j] *= ph[j]  (r14/r15 algebra, packed) ----
#pragma unroll
    for (int j = 0; j < DIM; ++j) {
        const float pr_ = s_phr[j], pi_ = s_phi[j];
        const f2 re = sre[j], im = sim[j];
        sre[j] = re * pr_ - im * pi_;
        sim[j] = re * pi_ + im * pr_;
    }

    // ---- layer 1: 5 real RY butterflies on pi1-composed indices (r15 verbatim) ----
#pragma unroll
    for (int q = 0; q < N_QUBITS; ++q) {
        const float c = s_cs[q][0], s = s_cs[q][1];
        const int stride = 1 << (4 - q);
        const int mask = stride - 1;
#pragma unroll
        for (int p = 0; p < DIM / 2; ++p) {
            const int a0 = ((p & ~mask) << 1) | (p & mask);
            const int ia = layer_perm(a0, 1);
            const int ib = layer_perm(a0 + stride, 1);
            const f2 ar = sre[ia], ai = sim[ia];
            const f2 br = sre[ib], bi = sim[ib];
            sre[ia] = c * ar - s * br;
            sim[ia] = c * ai - s * bi;
            sre[ib] = s * ar + c * br;
            sim[ib] = s * ai + c * bi;
        }
    }

    // ---- probs, both perms folded (r15 verbatim) ----
    f2 pr[DIM];
#pragma unroll
    for (int i = 0; i < DIM; ++i) {
        const int j = layer_perm(layer_perm(i, 2), 1);
        pr[i] = sre[j] * sre[j] + sim[j] * sim[j];
    }

    // ---- expvals via Walsh-Hadamard partial-sum tree (r15 verbatim) ----
    f2 v16[16], v8_[8], v4_[4], v2_[2];
    f2 ev4 = f2{0.f, 0.f}, ev3 = f2{0.f, 0.f}, ev2 = f2{0.f, 0.f}, ev1 = f2{0.f, 0.f};
#pragma unroll
    for (int j = 0; j < 16; ++j) { v16[j] = pr[2*j] + pr[2*j+1]; ev4 += pr[2*j] - pr[2*j+1]; }
#pragma unroll
    for (int j = 0; j < 8; ++j)  { v8_[j] = v16[2*j] + v16[2*j+1]; ev3 += v16[2*j] - v16[2*j+1]; }
#pragma unroll
    for (int j = 0; j < 4; ++j)  { v4_[j] = v8_[2*j] + v8_[2*j+1]; ev2 += v8_[2*j] - v8_[2*j+1]; }
#pragma unroll
    for (int j = 0; j < 2; ++j)  { v2_[j] = v4_[2*j] + v4_[2*j+1]; ev1 += v4_[2*j] - v4_[2*j+1]; }
    const f2 ev0 = v2_[0] - v2_[1];
    const f2 ev[N_QUBITS] = {ev0, ev1, ev2, ev3, ev4};

    // ---- FC (packed over both batches, r15 verbatim) ----
    f2 o[8];
#pragma unroll
    for (int j = 0; j < 8; ++j) {
        f2 acc = f2{s_fc_b[j], s_fc_b[j]};
#pragma unroll
        for (int q = 0; q < 5; ++q) acc += ev[q] * s_fc_w[j * 5 + q];
        o[j] = acc;
    }

    // ---- stores: two coalesced float4 pairs (r15 verbatim) ----
    float4* op0 = (float4*)(out + (size_t)b0 * 8);
    op0[0] = make_float4(o[0].x, o[1].x, o[2].x, o[3].x);
    op0[1] = make_float4(o[4].x, o[5].x, o[6].x, o[7].x);
    if (b1 < Btot) {
        float4* op1 = (float4*)(out + (size_t)b1 * 8);
        op1[0] = make_float4(o[0].y, o[1].y, o[2].y, o[3].y);
        op1[1] = make_float4(o[4].y, o[5].y, o[6].y, o[7].y);
    }
}

extern "C" void kernel_launch(void* const* d_in, const int* in_sizes, int n_in,
                              void* d_out, int out_size, void* d_ws, size_t ws_size,
                              hipStream_t stream) {
    const float* x    = (const float*)d_in[0];
    const float* w    = (const float*)d_in[1];
    const float* fc_w = (const float*)d_in[2];
    const float* fc_b = (const float*)d_in[3];
    float* out = (float*)d_out;

    const int Btot = in_sizes[0] / N_QUBITS;   // 262144
    const int grid = (Btot + 511) / 512;       // 2 batches per thread
    hipLaunchKernelGGL(vqc_kernel, dim3(grid), dim3(256), 0, stream,
                       x, w, fc_w, fc_b, out, Btot);
}

// Round 18
// 14.915 us; speedup vs baseline: 1.0769x; 1.0769x over previous
//
#include <hip/hip_runtime.h>

typedef float f2 __attribute__((ext_vector_type(2)));

#define N_QUBITS 5
#define DIM 32

// ---------- verified perm machinery (rounds 1/2/7-16) ----------
__host__ __device__ constexpr int cnot_apply(int i, int ctrl, int tgt) {
    const int pc = N_QUBITS - 1 - ctrl;
    const int pt = N_QUBITS - 1 - tgt;
    return i ^ (((i >> pc) & 1) << pt);
}
__host__ __device__ constexpr int layer_perm(int i, int r) {
    int idx = i;
    for (int q = N_QUBITS - 1; q >= 0; --q)
        idx = cnot_apply(idx, q, (q + r) % N_QUBITS);
    return idx;
}
__host__ __device__ constexpr int invP1(int p) {   // inverse of layer_perm(.,1)
    for (int l = 0; l < 32; ++l) if (layer_perm(l, 1) == p) return l;
    return 0;
}

// r15 (best verified: 14.91us) with ONE micro-change: phi-diagonal table packed
// as f2 -> one ds_read_b64/slot instead of two ds_read_b32.
// NOTE (r17 lesson): D_phi does NOT tensor-factor through the CNOT layer (pi1
// mixes bits over GF(2)); the 32-entry table is the correct application.
__global__ __launch_bounds__(256, 2) void vqc_kernel(
    const float* __restrict__ x,      // (B, 5)
    const float* __restrict__ w,      // (2, 5, 3)
    const float* __restrict__ fc_w,   // (8, 5)
    const float* __restrict__ fc_b,   // (8,)
    float* __restrict__ out,          // (B, 8)
    int Btot)
{
    // ---- block-uniform precompute (r14/r15-verified) ----
    __shared__ float s_g0[N_QUBITS][8];   // layer 0: full Rot coeffs
    __shared__ float s_cs[N_QUBITS][2];   // layer 1: (cos(th/2), sin(th/2))
    __shared__ f2    s_ph[DIM];           // layer-1 phi-diagonal {re, im}, packed
    __shared__ float s_fc_w[40];
    __shared__ float s_fc_b[8];

    const int t = threadIdx.x;
    if (t < N_QUBITS) {                   // layer-0 gates: full matrix
        const float phi = w[t * 3 + 0];
        const float th  = w[t * 3 + 1];
        const float om  = w[t * 3 + 2];
        float s, c;   sincosf(0.5f * th, &s, &c);
        float sp, cp; sincosf(0.5f * (phi + om), &sp, &cp);
        float sm, cm; sincosf(0.5f * (phi - om), &sm, &cm);
        s_g0[t][0] =  cp * c;  s_g0[t][1] = -sp * c;   // g00
        s_g0[t][2] = -cm * s;  s_g0[t][3] = -sm * s;   // g01
        s_g0[t][4] =  cm * s;  s_g0[t][5] = -sm * s;   // g10
        s_g0[t][6] =  cp * c;  s_g0[t][7] =  sp * c;   // g11
    } else if (t >= 8 && t < 13) {        // layer-1 RY coeffs
        const int q = t - 8;
        float s, c;
        sincosf(0.5f * w[(N_QUBITS + q) * 3 + 1], &s, &c);
        s_cs[q][0] = c;  s_cs[q][1] = s;
    } else if (t >= 32 && t < 64) {       // layer-1 phi-diagonal (32 phases)
        const int j = t - 32;
        const int i = invP1(j);
        float ang = 0.f;
#pragma unroll
        for (int q = 0; q < N_QUBITS; ++q) {
            const float ph = w[(N_QUBITS + q) * 3 + 0];
            ang += ((i >> (4 - q)) & 1) ? 0.5f * ph : -0.5f * ph;
        }
        float s, c;
        sincosf(ang, &s, &c);
        s_ph[j] = f2{c, s};
    } else if (t >= 64 && t < 104) {
        s_fc_w[t - 64] = fc_w[t - 64];
    } else if (t >= 104 && t < 112) {
        s_fc_b[t - 104] = fc_b[t - 104];
    }
    __syncthreads();

    const int b0 = blockIdx.x * 512 + t;
    if (b0 >= Btot) return;
    const int b1 = b0 + 256;
    const int b1c = (b1 < Btot) ? b1 : b0;        // clamp for loads only

    const float* xp0 = x + (size_t)b0 * 5;
    const float* xp1 = x + (size_t)b1c * 5;

    // ---- build: post-layer-0 product state (r15 verbatim, packed f2 SoA) ----
    f2 sre[DIM], sim[DIM];
    {
        float s0, c0, s1, c1;
        __sincosf(0.5f * xp0[0], &s0, &c0);
        __sincosf(0.5f * xp1[0], &s1, &c1);
        const f2 cc = f2{c0, c1}, ss = f2{s0, s1};
        sre[0]  = s_g0[0][0] * cc + s_g0[0][3] * ss;
        sim[0]  = s_g0[0][1] * cc - s_g0[0][2] * ss;
        sre[16] = s_g0[0][4] * cc + s_g0[0][7] * ss;
        sim[16] = s_g0[0][5] * cc - s_g0[0][6] * ss;
    }
#pragma unroll
    for (int q = 1; q < N_QUBITS; ++q) {
        float s0, c0, s1, c1;
        __sincosf(0.5f * xp0[q], &s0, &c0);
        __sincosf(0.5f * xp1[q], &s1, &c1);
        const f2 cc = f2{c0, c1}, ss = f2{s0, s1};
        const f2 v0re = s_g0[q][0] * cc + s_g0[q][3] * ss;
        const f2 v0im = s_g0[q][1] * cc - s_g0[q][2] * ss;
        const f2 v1re = s_g0[q][4] * cc + s_g0[q][7] * ss;
        const f2 v1im = s_g0[q][5] * cc - s_g0[q][6] * ss;
        const int stride = 1 << (4 - q);
#pragma unroll
        for (int k = 0; k < (1 << q); ++k) {
            const int m = k * (stride << 1);
            const f2 are = sre[m], aim = sim[m];
            sre[m + stride] = v1re * are - v1im * aim;
            sim[m + stride] = v1re * aim + v1im * are;
            sre[m]          = v0re * are - v0im * aim;
            sim[m]          = v0re * aim + v0im * are;
        }
    }

    // ---- layer-1 phi-diagonal: st[j] *= ph[j]  (packed table read) ----
#pragma unroll
    for (int j = 0; j < DIM; ++j) {
        const f2 ph = s_ph[j];                 // one ds_read_b64
        const f2 re = sre[j], im = sim[j];
        sre[j] = re * ph.x - im * ph.y;
        sim[j] = re * ph.y + im * ph.x;
    }

    // ---- layer 1: 5 real RY butterflies on pi1-composed indices (r15 verbatim) ----
#pragma unroll
    for (int q = 0; q < N_QUBITS; ++q) {
        const float c = s_cs[q][0], s = s_cs[q][1];
        const int stride = 1 << (4 - q);
        const int mask = stride - 1;
#pragma unroll
        for (int p = 0; p < DIM / 2; ++p) {
            const int a0 = ((p & ~mask) << 1) | (p & mask);
            const int ia = layer_perm(a0, 1);
            const int ib = layer_perm(a0 + stride, 1);
            const f2 ar = sre[ia], ai = sim[ia];
            const f2 br = sre[ib], bi = sim[ib];
            sre[ia] = c * ar - s * br;
            sim[ia] = c * ai - s * bi;
            sre[ib] = s * ar + c * br;
            sim[ib] = s * ai + c * bi;
        }
    }

    // ---- probs, both perms folded (r15 verbatim) ----
    f2 pr[DIM];
#pragma unroll
    for (int i = 0; i < DIM; ++i) {
        const int j = layer_perm(layer_perm(i, 2), 1);
        pr[i] = sre[j] * sre[j] + sim[j] * sim[j];
    }

    // ---- expvals via Walsh-Hadamard partial-sum tree (r15 verbatim) ----
    f2 v16[16], v8_[8], v4_[4], v2_[2];
    f2 ev4 = f2{0.f, 0.f}, ev3 = f2{0.f, 0.f}, ev2 = f2{0.f, 0.f}, ev1 = f2{0.f, 0.f};
#pragma unroll
    for (int j = 0; j < 16; ++j) { v16[j] = pr[2*j] + pr[2*j+1]; ev4 += pr[2*j] - pr[2*j+1]; }
#pragma unroll
    for (int j = 0; j < 8; ++j)  { v8_[j] = v16[2*j] + v16[2*j+1]; ev3 += v16[2*j] - v16[2*j+1]; }
#pragma unroll
    for (int j = 0; j < 4; ++j)  { v4_[j] = v8_[2*j] + v8_[2*j+1]; ev2 += v8_[2*j] - v8_[2*j+1]; }
#pragma unroll
    for (int j = 0; j < 2; ++j)  { v2_[j] = v4_[2*j] + v4_[2*j+1]; ev1 += v4_[2*j] - v4_[2*j+1]; }
    const f2 ev0 = v2_[0] - v2_[1];
    const f2 ev[N_QUBITS] = {ev0, ev1, ev2, ev3, ev4};

    // ---- FC (packed over both batches, r15 verbatim) ----
    f2 o[8];
#pragma unroll
    for (int j = 0; j < 8; ++j) {
        f2 acc = f2{s_fc_b[j], s_fc_b[j]};
#pragma unroll
        for (int q = 0; q < 5; ++q) acc += ev[q] * s_fc_w[j * 5 + q];
        o[j] = acc;
    }

    // ---- stores: two coalesced float4 pairs (r15 verbatim) ----
    float4* op0 = (float4*)(out + (size_t)b0 * 8);
    op0[0] = make_float4(o[0].x, o[1].x, o[2].x, o[3].x);
    op0[1] = make_float4(o[4].x, o[5].x, o[6].x, o[7].x);
    if (b1 < Btot) {
        float4* op1 = (float4*)(out + (size_t)b1 * 8);
        op1[0] = make_float4(o[0].y, o[1].y, o[2].y, o[3].y);
        op1[1] = make_float4(o[4].y, o[5].y, o[6].y, o[7].y);
    }
}

extern "C" void kernel_launch(void* const* d_in, const int* in_sizes, int n_in,
                              void* d_out, int out_size, void* d_ws, size_t ws_size,
                              hipStream_t stream) {
    const float* x    = (const float*)d_in[0];
    const float* w    = (const float*)d_in[1];
    const float* fc_w = (const float*)d_in[2];
    const float* fc_b = (const float*)d_in[3];
    float* out = (float*)d_out;

    const int Btot = in_sizes[0] / N_QUBITS;   // 262144
    const int grid = (Btot + 511) / 512;       // 2 batches per thread
    hipLaunchKernelGGL(vqc_kernel, dim3(grid), dim3(256), 0, stream,
                       x, w, fc_w, fc_b, out, Btot);
}

// Round 19
// 14.328 us; speedup vs baseline: 1.1210x; 1.0410x over previous
//
#include <hip/hip_runtime.h>

typedef float f2 __attribute__((ext_vector_type(2)));

#define N_QUBITS 5
#define DIM 32

// ---------- verified perm machinery (rounds 1/2/7-18) ----------
__host__ __device__ constexpr int cnot_apply(int i, int ctrl, int tgt) {
    const int pc = N_QUBITS - 1 - ctrl;
    const int pt = N_QUBITS - 1 - tgt;
    return i ^ (((i >> pc) & 1) << pt);
}
__host__ __device__ constexpr int layer_perm(int i, int r) {
    int idx = i;
    for (int q = N_QUBITS - 1; q >= 0; --q)
        idx = cnot_apply(idx, q, (q + r) % N_QUBITS);
    return idx;
}
__host__ __device__ constexpr int invP(int p, int r) {
    for (int l = 0; l < 32; ++l) if (layer_perm(l, r) == p) return l;
    return 0;
}
__host__ __device__ constexpr int pc5(int m) {
    int c = 0;
    for (int b = 0; b < 5; ++b) c += (m >> b) & 1;
    return c;
}
__host__ __device__ constexpr int pow3(int n) {
    int r = 1;
    for (int i = 0; i < n; ++i) r *= 3;
    return r;
}
// Z_q pulled back through pi2 (linear): bit b of M = bit_{4-q}(invP2(e_b)).
// Consistency: with diagonal layer-1 this reproduces r15's VERIFIED decode
// functional bit_{4-q}(invP2(invP1(j))) after the pi1 step below.
__host__ __device__ constexpr int Mmask(int q) {
    int m = 0;
    for (int b = 0; b < 5; ++b)
        m |= ((invP(1 << b, 2) >> (4 - q)) & 1) << b;
    return m;
}
__host__ __device__ constexpr int NC(int q) { return pow3(pc5(Mmask(q))); }

// One Pauli string: choice C assigns {Z,X,Y} to each bit of Mmask(Q);
// conjugated through pi1 via the GF(2)-symplectic closed form.
struct SInfo {
    int sign;      // +1 / -1  (i^{pc(x&z)-pc(x'&z')})
    int nf;        // coefficient factors (= |M|)
    int fidx[5];   // indices into a[15]: a[b*3+t], t: 0=Z,1=X,2=Y
    int k;         // final support size
    int eb[5];     // final support bit positions
    int et[5];     // final types: 0=Z,1=X,2=Y
};

__host__ __device__ constexpr SInfo make_sinfo(int Q, int C) {
    SInfo s{};
    const int M = Mmask(Q);
    int x = 0, z = 0, c = C;
    s.nf = 0;
    for (int b = 0; b < 5; ++b) {
        if ((M >> b) & 1) {
            const int t = c % 3; c /= 3;
            s.fidx[s.nf] = b * 3 + t;
            s.nf++;
            if (t == 0)      z |= 1 << b;            // Z
            else if (t == 1) x |= 1 << b;            // X
            else           { x |= 1 << b; z |= 1 << b; }  // Y = i XZ
        }
    }
    // pull back through pi1: X^x -> X^{sigma1(x)}; Z^z -> z' with
    // z'_b = parity(z & invP1(e_b)); sign from canonical-form phase.
    const int xp = layer_perm(x, 1);
    int zp = 0;
    for (int b = 0; b < 5; ++b)
        zp |= (pc5(z & invP(1 << b, 1)) & 1) << b;
    const int d  = pc5(x & z) - pc5(xp & zp);
    const int dm = ((d % 4) + 4) % 4;                // 0 or 2 (symplectic)
    s.sign = (dm == 0) ? 1 : -1;
    s.k = 0;
    for (int b = 0; b < 5; ++b) {
        const int tx = (xp >> b) & 1, tz = (zp >> b) & 1;
        if (tx | tz) {
            s.eb[s.k] = b;
            s.et[s.k] = tx ? (tz ? 2 : 1) : 0;
            s.k++;
        }
    }
    return s;
}

#define EPICK(T, B) ((T) == 0 ? EZ[B] : ((T) == 1 ? EX[B] : EY[B]))

template<int Q, int C>
__device__ __forceinline__ f2 sterm(const float (&a)[15],
        const f2 (&EZ)[5], const f2 (&EX)[5], const f2 (&EY)[5]) {
    constexpr SInfo s = make_sinfo(Q, C);   // forced compile-time (r11 lesson)
    float cf = a[s.fidx[0]];
    if constexpr (s.nf > 1) cf *= a[s.fidx[1]];
    if constexpr (s.nf > 2) cf *= a[s.fidx[2]];
    if constexpr (s.nf > 3) cf *= a[s.fidx[3]];
    if constexpr (s.nf > 4) cf *= a[s.fidx[4]];
    f2 e = EPICK(s.et[0], s.eb[0]);
    if constexpr (s.k > 1) e = e * EPICK(s.et[1], s.eb[1]);
    if constexpr (s.k > 2) e = e * EPICK(s.et[2], s.eb[2]);
    if constexpr (s.k > 3) e = e * EPICK(s.et[3], s.eb[3]);
    if constexpr (s.k > 4) e = e * EPICK(s.et[4], s.eb[4]);
    if constexpr (s.sign < 0) return e * (-cf);
    else                      return e * cf;
}

template<int Q, int C>
struct SSum {
    static __device__ __forceinline__ f2 go(const float (&a)[15],
            const f2 (&EZ)[5], const f2 (&EX)[5], const f2 (&EY)[5]) {
        return SSum<Q, C - 1>::go(a, EZ, EX, EY) + sterm<Q, C>(a, EZ, EX, EY);
    }
};
template<int Q>
struct SSum<Q, 0> {
    static __device__ __forceinline__ f2 go(const float (&a)[15],
            const f2 (&EZ)[5], const f2 (&EX)[5], const f2 (&EY)[5]) {
        return sterm<Q, 0>(a, EZ, EX, EY);
    }
};

// Heisenberg-picture kernel: no 32-component state, no butterflies.
// ev_q = sum over Pauli strings of coef * prod of per-qubit expectations.
__global__ __launch_bounds__(256, 4) void vqc_kernel(
    const float* __restrict__ x,      // (B, 5)
    const float* __restrict__ w,      // (2, 5, 3)
    const float* __restrict__ fc_w,   // (8, 5)
    const float* __restrict__ fc_b,   // (8,)
    float* __restrict__ out,          // (B, 8)
    int Btot)
{
    __shared__ float s_g0[N_QUBITS][8];   // layer 0: full Rot coeffs (r15-verified)
    __shared__ float s_a[15];             // a[b*3+t]: Heisenberg coefs per bit b
    __shared__ float s_fc_w[40];
    __shared__ float s_fc_b[8];

    const int t = threadIdx.x;
    if (t < N_QUBITS) {                   // layer-0 gates: full matrix (r15 verbatim)
        const float phi = w[t * 3 + 0];
        const float th  = w[t * 3 + 1];
        const float om  = w[t * 3 + 2];
        float s, c;   sincosf(0.5f * th, &s, &c);
        float sp, cp; sincosf(0.5f * (phi + om), &sp, &cp);
        float sm, cm; sincosf(0.5f * (phi - om), &sm, &cm);
        s_g0[t][0] =  cp * c;  s_g0[t][1] = -sp * c;   // g00
        s_g0[t][2] = -cm * s;  s_g0[t][3] = -sm * s;   // g01
        s_g0[t][4] =  cm * s;  s_g0[t][5] = -sm * s;   // g10
        s_g0[t][6] =  cp * c;  s_g0[t][7] =  sp * c;   // g11
    } else if (t >= 8 && t < 13) {        // layer-1 Heisenberg coefs (FULL angles)
        const int q = t - 8;
        const float phi = w[(N_QUBITS + q) * 3 + 0];
        const float th  = w[(N_QUBITS + q) * 3 + 1];
        float sth, cth; sincosf(th,  &sth, &cth);
        float sph, cph; sincosf(phi, &sph, &cph);
        const int b = 4 - q;              // qubit q lives at bit 4-q
        s_a[b * 3 + 0] = cth;             // Z coef
        s_a[b * 3 + 1] = -sth * cph;      // X coef
        s_a[b * 3 + 2] =  sth * sph;      // Y coef
    } else if (t >= 64 && t < 104) {
        s_fc_w[t - 64] = fc_w[t - 64];
    } else if (t >= 104 && t < 112) {
        s_fc_b[t - 104] = fc_b[t - 104];
    }
    __syncthreads();

    const int b0 = blockIdx.x * 512 + t;
    if (b0 >= Btot) return;
    const int b1 = b0 + 256;
    const int b1c = (b1 < Btot) ? b1 : b0;        // clamp for loads only

    const float* xp0 = x + (size_t)b0 * 5;
    const float* xp1 = x + (size_t)b1c * 5;

    // ---- per-qubit v = Rot0_q RX(x_q)|0>  (r15-verified formulas) and
    //      Pauli expectations EZ/EX/EY (2 batches packed) ----
    f2 EZ[5], EX[5], EY[5];
#pragma unroll
    for (int q = 0; q < N_QUBITS; ++q) {
        float s0, c0, s1, c1;
        __sincosf(0.5f * xp0[q], &s0, &c0);
        __sincosf(0.5f * xp1[q], &s1, &c1);
        const f2 cc = f2{c0, c1}, ss = f2{s0, s1};
        const f2 v0re = s_g0[q][0] * cc + s_g0[q][3] * ss;
        const f2 v0im = s_g0[q][1] * cc - s_g0[q][2] * ss;
        const f2 v1re = s_g0[q][4] * cc + s_g0[q][7] * ss;
        const f2 v1im = s_g0[q][5] * cc - s_g0[q][6] * ss;
        const int b = 4 - q;
        EZ[b] = v0re * v0re + v0im * v0im - v1re * v1re - v1im * v1im;
        EX[b] = 2.f * (v0re * v1re + v0im * v1im);
        EY[b] = 2.f * (v0re * v1im - v0im * v1re);
    }

    float a[15];
#pragma unroll
    for (int i = 0; i < 15; ++i) a[i] = s_a[i];

    // ---- expvals: compile-time Pauli-string sums ----
    f2 ev[N_QUBITS];
    ev[0] = SSum<0, NC(0) - 1>::go(a, EZ, EX, EY);
    ev[1] = SSum<1, NC(1) - 1>::go(a, EZ, EX, EY);
    ev[2] = SSum<2, NC(2) - 1>::go(a, EZ, EX, EY);
    ev[3] = SSum<3, NC(3) - 1>::go(a, EZ, EX, EY);
    ev[4] = SSum<4, NC(4) - 1>::go(a, EZ, EX, EY);

    // ---- FC (packed over both batches, r15 verbatim) ----
    f2 o[8];
#pragma unroll
    for (int j = 0; j < 8; ++j) {
        f2 acc = f2{s_fc_b[j], s_fc_b[j]};
#pragma unroll
        for (int q = 0; q < 5; ++q) acc += ev[q] * s_fc_w[j * 5 + q];
        o[j] = acc;
    }

    // ---- stores: two coalesced float4 pairs (r15 verbatim) ----
    float4* op0 = (float4*)(out + (size_t)b0 * 8);
    op0[0] = make_float4(o[0].x, o[1].x, o[2].x, o[3].x);
    op0[1] = make_float4(o[4].x, o[5].x, o[6].x, o[7].x);
    if (b1 < Btot) {
        float4* op1 = (float4*)(out + (size_t)b1 * 8);
        op1[0] = make_float4(o[0].y, o[1].y, o[2].y, o[3].y);
        op1[1] = make_float4(o[4].y, o[5].y, o[6].y, o[7].y);
    }
}

extern "C" void kernel_launch(void* const* d_in, const int* in_sizes, int n_in,
                              void* d_out, int out_size, void* d_ws, size_t ws_size,
                              hipStream_t stream) {
    const float* x    = (const float*)d_in[0];
    const float* w    = (const float*)d_in[1];
    const float* fc_w = (const float*)d_in[2];
    const float* fc_b = (const float*)d_in[3];
    float* out = (float*)d_out;

    const int Btot = in_sizes[0] / N_QUBITS;   // 262144
    const int grid = (Btot + 511) / 512;       // 2 batches per thread
    hipLaunchKernelGGL(vqc_kernel, dim3(grid), dim3(256), 0, stream,
                       x, w, fc_w, fc_b, out, Btot);
}